// Round 3
// baseline (195.085 us; speedup 1.0000x reference)
//
#include <hip/hip_runtime.h>
#include <hip/hip_bf16.h>
#include <math.h>

// Problem constants
#define NB      32
#define DDIM    256
#define HWSZ    1024                 // H*W
#define NTOK    32768                // NB*HWSZ
#define KCB     1024                 // codebook size
#define BSTRIDE (DDIM*HWSZ)          // floats per batch image

// ws layout (bytes); total ~525 KB
#define OFF_ESQ  0                   // 1024 f32
#define OFF_SW   4096                // 1024*256 bf16, tile-swizzled (512 KB)
#define OFF_CNT  528384              // 1024 u32
#define OFF_PART 532480              // 512 double

typedef __attribute__((ext_vector_type(8))) short s8v;   // 8 bf16 (4 VGPR)
typedef __attribute__((ext_vector_type(4))) float f4v;   // MFMA acc

__device__ __forceinline__ unsigned short f2bf(float x) {
    __hip_bfloat16 h = __float2bfloat16(x);
    return __builtin_bit_cast(unsigned short, h);
}

typedef __attribute__((address_space(3))) unsigned       lds_u32;
typedef const __attribute__((address_space(1))) unsigned glob_u32;

__device__ __forceinline__ void glds16(const void* g, void* l) {
    __builtin_amdgcn_global_load_lds((glob_u32*)g, (lds_u32*)l, 16, 0, 0);
}

// ---------------------------------------------------------------- esq (fp32, exact)
__global__ __launch_bounds__(256) void k_esq(const float* __restrict__ E,
                                             float* __restrict__ esq) {
    int w = threadIdx.x >> 6, lane = threadIdx.x & 63;
    int code = blockIdx.x * 4 + w;                   // grid 256 -> 1024
    const float4 v = *reinterpret_cast<const float4*>(&E[(size_t)code * DDIM + lane * 4]);
    double s = (double)v.x * v.x + (double)v.y * v.y +
               (double)v.z * v.z + (double)v.w * v.w;
    for (int off = 32; off; off >>= 1) s += __shfl_down(s, off, 64);
    if (lane == 0) esq[code] = (float)s;
}

// ---------------------------------------------------------------- E -> bf16, pre-swizzled tiles
// Ebf_sw layout: tile(ct,kc) of 16 KB = [128 codes][8 chunks of 16B]; physical chunk p
// holds source d-chunk jsrc = p ^ (code&7), so a LINEAR global_load_lds image gives
// swizzled LDS for conflict-free ds_read_b128.
__global__ __launch_bounds__(256) void k_sw(const float* __restrict__ E,
                                            unsigned short* __restrict__ Esw,
                                            unsigned* __restrict__ counts) {
    int g = blockIdx.x * 256 + threadIdx.x;          // grid 128 -> 32768 chunks
    if (g < KCB) counts[g] = 0u;                     // re-zero histogram every call
    int code = g >> 5, l = g & 31;
    int kc = l >> 3, p = l & 7;
    int jsrc = p ^ (code & 7);
    const float* src = &E[(size_t)code * DDIM + kc * 64 + jsrc * 8];
    const float4 v0 = *reinterpret_cast<const float4*>(src);
    const float4 v1 = *reinterpret_cast<const float4*>(src + 4);
    unsigned q0 = (unsigned)f2bf(v0.x) | ((unsigned)f2bf(v0.y) << 16);
    unsigned q1 = (unsigned)f2bf(v0.z) | ((unsigned)f2bf(v0.w) << 16);
    unsigned q2 = (unsigned)f2bf(v1.x) | ((unsigned)f2bf(v1.y) << 16);
    unsigned q3 = (unsigned)f2bf(v1.z) | ((unsigned)f2bf(v1.w) << 16);
    uint4 pk = {q0, q1, q2, q3};
    size_t dst = (size_t)((code >> 7) * 4 + kc) * 8192 + (code & 127) * 64 + p * 8; // u16 units
    *reinterpret_cast<uint4*>(&Esw[dst]) = pk;
}

// ---------------------------------------------------------------- fused main
// grid 512 blocks x 64 tokens; 256 thr = 4 waves, N-split over the 128-code B tile.
// A (64 tok x 256 d) -> LDS once -> VGPR frags (full K). Loop 8 ct x 4 kc staging
// B[128][64] via global_load_lds (2-phase prefetch). Argmin in 22-bit keys.
// Fused epilogue: histogram + Zq straight-through + diff^2 partials.
__global__ __launch_bounds__(256, 2) void k_main(const float* __restrict__ in,
                                                 const float* __restrict__ E,
                                                 const unsigned short* __restrict__ Esw,
                                                 const float* __restrict__ esq,
                                                 unsigned* __restrict__ counts,
                                                 double* __restrict__ partials,
                                                 float* __restrict__ out) {
    __shared__ union {
        unsigned short A[64 * 256];                  // 32 KB staging
        struct {
            unsigned key[4][64];                     // per-wave per-token best keys
            unsigned idx[64];                        // final code per token
            double   sd[256];                        // block reduce
        } ep;
    } sm;
    __shared__ unsigned short Bs[2][128 * 64];       // 2 x 16 KB

    const int t = threadIdx.x;
    const int lane = t & 63, w = t >> 6;
    const int lrow = lane & 15, lk = lane >> 4;
    const int n0 = blockIdx.x * 64;
    const int b = n0 >> 10, hw0 = n0 & 1023;
    const float* inb = in + (size_t)b * BSTRIDE + hw0;

    // ---- prefetch B tile 0 (overlaps A staging)
#pragma unroll
    for (int i = 0; i < 4; ++i)
        glds16(Esw + (size_t)(w * 4 + i) * 512 + lane * 8, &Bs[0][(w * 4 + i) * 512]);

    // ---- stage A: [64 tok][256 d] bf16, chunk-XOR swizzle (one-time)
    {
        const int tok = t & 63, dsub = t >> 6;
#pragma unroll
        for (int i = 0; i < 8; ++i) {
            const int d0 = dsub * 64 + i * 8;
            float v[8];
#pragma unroll
            for (int j = 0; j < 8; ++j) v[j] = inb[(size_t)(d0 + j) * HWSZ + tok];
            unsigned q0 = (unsigned)f2bf(v[0]) | ((unsigned)f2bf(v[1]) << 16);
            unsigned q1 = (unsigned)f2bf(v[2]) | ((unsigned)f2bf(v[3]) << 16);
            unsigned q2 = (unsigned)f2bf(v[4]) | ((unsigned)f2bf(v[5]) << 16);
            unsigned q3 = (unsigned)f2bf(v[6]) | ((unsigned)f2bf(v[7]) << 16);
            uint4 pk = {q0, q1, q2, q3};
            const int c = dsub * 8 + i;
            *reinterpret_cast<uint4*>(&sm.A[tok * 256 + ((c ^ (tok & 7)) * 8)]) = pk;
        }
    }
    __syncthreads();                                  // drains A writes + B tile-0 glds

    // ---- A fragments -> VGPR (full K=256): a[mi][sk], row = mi*16+lrow, k = sk*32+lk*8
    s8v a[4][8];
#pragma unroll
    for (int mi = 0; mi < 4; ++mi)
#pragma unroll
        for (int sk = 0; sk < 8; ++sk)
            a[mi][sk] = *reinterpret_cast<const s8v*>(
                &sm.A[(mi * 16 + lrow) * 256 + (((sk * 4 + lk) ^ (lrow & 7)) * 8)]);

    // ---- main loop: 8 code-tiles x 4 k-chunks
    unsigned best[16];
#pragma unroll
    for (int i = 0; i < 16; ++i) best[i] = 0xFFFFFFFFu;

    f4v acc[4][2];
    float es[2];

    for (int s = 0; s < 32; ++s) {
        const int ct = s >> 2, kc = s & 3;
        if (kc == 0) {
#pragma unroll
            for (int ni = 0; ni < 2; ++ni) {
                es[ni] = esq[ct * 128 + w * 32 + ni * 16 + lrow];
#pragma unroll
                for (int mi = 0; mi < 4; ++mi) acc[mi][ni] = (f4v){0.f, 0.f, 0.f, 0.f};
            }
        }
        if (s < 31) {                                 // prefetch next B tile
            const unsigned short* src = Esw + (size_t)(s + 1) * 8192;
            unsigned short* dst = Bs[(s + 1) & 1];
#pragma unroll
            for (int i = 0; i < 4; ++i)
                glds16(src + (size_t)(w * 4 + i) * 512 + lane * 8, dst + (w * 4 + i) * 512);
        }
        const unsigned short* bb = Bs[s & 1];
#pragma unroll
        for (int ks = 0; ks < 2; ++ks) {
            s8v bfr[2];
#pragma unroll
            for (int ni = 0; ni < 2; ++ni) {
                const int crow = w * 32 + ni * 16 + lrow;
                bfr[ni] = *reinterpret_cast<const s8v*>(
                    &bb[crow * 64 + (((ks * 4 + lk) ^ (lrow & 7)) * 8)]);
            }
#pragma unroll
            for (int mi = 0; mi < 4; ++mi)
#pragma unroll
                for (int ni = 0; ni < 2; ++ni)
                    acc[mi][ni] = __builtin_amdgcn_mfma_f32_16x16x32_bf16(
                        a[mi][kc * 2 + ks], bfr[ni], acc[mi][ni], 0, 0, 0);
        }
        if (kc == 3) {                                // fold dist into 22-bit keys
#pragma unroll
            for (int mi = 0; mi < 4; ++mi)
#pragma unroll
                for (int r = 0; r < 4; ++r)
#pragma unroll
                    for (int ni = 0; ni < 2; ++ni) {
                        float dv = fmaf(-2.0f, acc[mi][ni][r], es[ni]);
                        unsigned u = __float_as_uint(dv);
                        u = (u & 0x80000000u) ? ~u : (u | 0x80000000u);
                        unsigned key = (u & 0xFFFFFC00u)
                                     | (unsigned)(ct * 128 + w * 32 + ni * 16 + lrow);
                        unsigned cur = best[mi * 4 + r];
                        best[mi * 4 + r] = key < cur ? key : cur;
                    }
        }
        __syncthreads();
    }

    // ---- cross-lane then cross-wave argmin
#pragma unroll
    for (int mi = 0; mi < 4; ++mi)
#pragma unroll
        for (int r = 0; r < 4; ++r) {
            unsigned k = best[mi * 4 + r];
#pragma unroll
            for (int off = 1; off < 16; off <<= 1) {
                unsigned o = __shfl_xor(k, off, 64);
                k = o < k ? o : k;
            }
            if (lrow == 0) sm.ep.key[w][mi * 16 + lk * 4 + r] = k;
        }
    __syncthreads();
    if (t < 64) {
        unsigned k = sm.ep.key[0][t];
#pragma unroll
        for (int j = 1; j < 4; ++j) {
            unsigned o = sm.ep.key[j][t];
            k = o < k ? o : k;
        }
        sm.ep.idx[t] = k & 1023u;
    }
    __syncthreads();

    // ---- histogram (block-dedup: one atomic per distinct code per block)
    if (t < 64) {
        unsigned my = sm.ep.idx[t];
        int cnt = 0; bool lead = true;
        for (int j = 0; j < 64; ++j) {
            unsigned v = sm.ep.idx[j];
            if (v == my) { ++cnt; if (j < t) lead = false; }
        }
        if (lead) atomicAdd(&counts[my], (unsigned)cnt);
    }

    // ---- fused epilogue: Zq straight-through + diff^2 (in-slice is L2-hot)
    {
        const int tok = t & 63;
        const unsigned idx = sm.ep.idx[tok];
        const float* zp = inb + tok;
        const float* ep = E + (size_t)idx * DDIM + w * 64;
        float* op = out + 1 + (size_t)b * BSTRIDE + (size_t)w * 64 * HWSZ + hw0 + tok;
        double sacc = 0.0;
#pragma unroll 4
        for (int i = 0; i < 64; ++i) {
            float ze = zp[(size_t)(w * 64 + i) * HWSZ];
            float zq = ep[i];
            float df = __fsub_rn(zq, ze);            // fl(zq - ze)
            op[(size_t)i * HWSZ] = __fadd_rn(ze, df);
            sacc += (double)__fmul_rn(df, df);
        }
        sm.ep.sd[t] = sacc;
    }
    __syncthreads();
    for (int off = 128; off; off >>= 1) {
        if (t < off) sm.ep.sd[t] += sm.ep.sd[t + off];
        __syncthreads();
    }
    if (t == 0) partials[blockIdx.x] = sm.ep.sd[0];
}

// ---------------------------------------------------------------- finalize
__global__ __launch_bounds__(256) void k_final(const double* __restrict__ partials,
                                               const unsigned* __restrict__ counts,
                                               float* __restrict__ out) {
    __shared__ double sd[256];
    int t = threadIdx.x;
    sd[t] = partials[t] + partials[t + 256];
    __syncthreads();
    for (int off = 128; off; off >>= 1) {
        if (t < off) sd[t] += sd[t + off];
        __syncthreads();
    }
    double msum = sd[0];
    __syncthreads();

    double es_ = 0.0;
#pragma unroll
    for (int j = 0; j < 4; ++j) {
        unsigned c = counts[t * 4 + j];
        float p = (float)c / 32768.0f;               // exact (div by 2^15)
        float term = __fmul_rn(p, log2f(__fadd_rn(p, 1e-10f)));
        es_ += (double)term;
    }
    sd[t] = es_; __syncthreads();
    for (int off = 128; off; off >>= 1) {
        if (t < off) sd[t] += sd[t + off];
        __syncthreads();
    }
    if (t == 0) {
        float e = (float)(msum / 8388608.0);         // mean over B*D*H*W
        float q = e;                                 // numerically identical in ref
        float loss = __fadd_rn(q, __fmul_rn(0.25f, e));
        float ent = -(float)sd[0];
        float words = exp2f(ent);
        out[0] = loss;
        out[1 + 8388608 + 0] = e;
        out[1 + 8388608 + 1] = q;
        out[1 + 8388608 + 2] = words;
    }
}

// ---------------------------------------------------------------- launch
extern "C" void kernel_launch(void* const* d_in, const int* in_sizes, int n_in,
                              void* d_out, int out_size, void* d_ws, size_t ws_size,
                              hipStream_t stream) {
    const float* in = (const float*)d_in[0];
    const float* E  = (const float*)d_in[1];
    float* out = (float*)d_out;
    char* ws = (char*)d_ws;
    float*          esq      = (float*)(ws + OFF_ESQ);
    unsigned short* Esw      = (unsigned short*)(ws + OFF_SW);
    unsigned*       counts   = (unsigned*)(ws + OFF_CNT);
    double*         partials = (double*)(ws + OFF_PART);

    hipLaunchKernelGGL(k_esq,  dim3(256), dim3(256), 0, stream, E, esq);
    hipLaunchKernelGGL(k_sw,   dim3(128), dim3(256), 0, stream, E, Esw, counts);
    hipLaunchKernelGGL(k_main, dim3(512), dim3(256), 0, stream,
                       in, E, Esw, esq, counts, partials, out);
    hipLaunchKernelGGL(k_final, dim3(1), dim3(256), 0, stream, partials, counts, out);
}

// Round 4
// 136.094 us; speedup vs baseline: 1.4335x; 1.4335x over previous
//
#include <hip/hip_runtime.h>
#include <hip/hip_bf16.h>
#include <math.h>

// Problem constants
#define NB      32
#define DDIM    256
#define HWSZ    1024                 // H*W
#define NTOK    32768                // NB*HWSZ
#define KCB     1024                 // codebook size
#define BSTRIDE (DDIM*HWSZ)          // floats per batch image

// ws layout (bytes)
#define OFF_ESQ  0                   // 1024 f32
#define OFF_SW   4096                // 1024*256 bf16, tile-swizzled (512 KB)
#define OFF_CNT  528384              // 1024 u32
#define OFF_PART 532480              // 256 double

typedef __attribute__((ext_vector_type(8))) short s8v;   // 8 bf16 (4 VGPR)
typedef __attribute__((ext_vector_type(4))) float f4v;   // MFMA acc

__device__ __forceinline__ unsigned short f2bf(float x) {
    __hip_bfloat16 h = __float2bfloat16(x);
    return __builtin_bit_cast(unsigned short, h);
}

typedef __attribute__((address_space(3))) unsigned       lds_u32;
typedef const __attribute__((address_space(1))) unsigned glob_u32;

__device__ __forceinline__ void glds16(const void* g, void* l) {
    __builtin_amdgcn_global_load_lds((glob_u32*)g, (lds_u32*)l, 16, 0, 0);
}

// ---------------------------------------------------------------- prep: esq + swizzled bf16 E + zero counts
// grid 128 x 256 thr; block = 8 codes x 32 threads (each thread: one 16B chunk = 8 floats)
__global__ __launch_bounds__(256) void k_prep(const float* __restrict__ E,
                                              float* __restrict__ esq,
                                              unsigned short* __restrict__ Esw,
                                              unsigned* __restrict__ counts) {
    const int t = threadIdx.x;
    const int g = blockIdx.x * 256 + t;
    if (g < KCB) counts[g] = 0u;

    const int code = blockIdx.x * 8 + (t >> 5);
    const int l = t & 31, kc = l >> 3, p = l & 7;
    const int jsrc = p ^ (code & 7);                 // pre-swizzle source chunk
    const float* src = &E[(size_t)code * DDIM + kc * 64 + jsrc * 8];
    const float4 v0 = *reinterpret_cast<const float4*>(src);
    const float4 v1 = *reinterpret_cast<const float4*>(src + 4);

    double s = (double)v0.x * v0.x + (double)v0.y * v0.y +
               (double)v0.z * v0.z + (double)v0.w * v0.w +
               (double)v1.x * v1.x + (double)v1.y * v1.y +
               (double)v1.z * v1.z + (double)v1.w * v1.w;
#pragma unroll
    for (int off = 1; off < 32; off <<= 1) s += __shfl_xor(s, off, 64);
    if (l == 0) esq[code] = (float)s;

    unsigned q0 = (unsigned)f2bf(v0.x) | ((unsigned)f2bf(v0.y) << 16);
    unsigned q1 = (unsigned)f2bf(v0.z) | ((unsigned)f2bf(v0.w) << 16);
    unsigned q2 = (unsigned)f2bf(v1.x) | ((unsigned)f2bf(v1.y) << 16);
    unsigned q3 = (unsigned)f2bf(v1.z) | ((unsigned)f2bf(v1.w) << 16);
    uint4 pk = {q0, q1, q2, q3};
    size_t dst = (size_t)((code >> 7) * 4 + kc) * 8192 + (code & 127) * 64 + p * 8;
    *reinterpret_cast<uint4*>(&Esw[dst]) = pk;
}

// ---------------------------------------------------------------- fused main
// grid 256 x 512 thr. Block owns 128 tokens, scans all 1024 codes (full K).
// 8 waves M-split (16 tokens each); A full-K in VGPR; B triple-buffered 16 KB
// chunks via global_load_lds with counted-vmcnt pipeline (no vmcnt(0) in loop).
__global__ __launch_bounds__(512) void k_main(const float* __restrict__ in,
                                              const float* __restrict__ E,
                                              const unsigned short* __restrict__ Esw,
                                              const float* __restrict__ esq,
                                              unsigned* __restrict__ counts,
                                              double* __restrict__ partials,
                                              float* __restrict__ out) {
    __shared__ __align__(16) unsigned short Bs[3][128 * 64];   // 48 KB
    __shared__ float    esq_lds[1024];                          // 4 KB
    __shared__ unsigned idx_lds[128];
    __shared__ double   sd[512];

    const int t = threadIdx.x;
    const int lane = t & 63, w = t >> 6;             // 8 waves
    const int lrow = lane & 15, lk = lane >> 4;
    const int n0 = blockIdx.x * 128;
    const int b = n0 >> 10, hw0 = n0 & 1023;         // 128 tokens in one image
    const float* inb = in + (size_t)b * BSTRIDE + hw0;

    esq_lds[t]       = esq[t];
    esq_lds[t + 512] = esq[t + 512];

    // ---- A-stage: 4 phases through Bs[2]; full-K fragments -> 32 VGPR/wave
    s8v a[8];
    const int arow = w * 16 + lrow;
    for (int kc = 0; kc < 4; ++kc) {
        __syncthreads();                             // WAR protection on Bs[2]
#pragma unroll
        for (int ci = 0; ci < 2; ++ci) {
            const int cid = t + ci * 512;
            const int tok = cid & 127, c = cid >> 7; // c 0..7 (ci=0: 0..3, ci=1: 4..7)
            const int d0 = kc * 64 + c * 8;
            float v[8];
#pragma unroll
            for (int j = 0; j < 8; ++j) v[j] = inb[(size_t)(d0 + j) * HWSZ + tok];
            unsigned q0 = (unsigned)f2bf(v[0]) | ((unsigned)f2bf(v[1]) << 16);
            unsigned q1 = (unsigned)f2bf(v[2]) | ((unsigned)f2bf(v[3]) << 16);
            unsigned q2 = (unsigned)f2bf(v[4]) | ((unsigned)f2bf(v[5]) << 16);
            unsigned q3 = (unsigned)f2bf(v[6]) | ((unsigned)f2bf(v[7]) << 16);
            uint4 pk = {q0, q1, q2, q3};
            *reinterpret_cast<uint4*>(&Bs[2][tok * 64 + ((c ^ (tok & 7)) * 8)]) = pk;
        }
        __syncthreads();
#pragma unroll
        for (int ks = 0; ks < 2; ++ks)
            a[kc * 2 + ks] = *reinterpret_cast<const s8v*>(
                &Bs[2][arow * 64 + (((ks * 4 + lk) ^ (arow & 7)) * 8)]);
    }
    // All waves' kc=3 fragment reads complete before anyone passes the first raw
    // barrier below; prologue glds touch only Bs[0]/Bs[1] -> no extra barrier.

    // ---- prologue: issue tiles 0,1 (2 glds-instr per wave per tile)
#pragma unroll
    for (int tp = 0; tp < 2; ++tp)
#pragma unroll
        for (int i = 0; i < 2; ++i)
            glds16(Esw + (size_t)tp * 8192 + (w * 2 + i) * 512 + lane * 8,
                   &Bs[tp][(w * 2 + i) * 512]);

    // ---- main loop: 8 code-tiles x 4 k-chunks, counted-vmcnt pipeline
    unsigned best[4] = {~0u, ~0u, ~0u, ~0u};
    f4v acc[8];
    float es[8];

    for (int ss = 0; ss < 8; ++ss) {
#pragma unroll
        for (int kcs = 0; kcs < 4; ++kcs) {
            const int s = ss * 4 + kcs;
            // drain tile s only (tile s+1 stays in flight across the barrier)
            if (s < 31) asm volatile("s_waitcnt vmcnt(2)" ::: "memory");
            else        asm volatile("s_waitcnt vmcnt(0)" ::: "memory");
            __builtin_amdgcn_s_barrier();
            if (s + 2 < 32) {                        // prefetch tile s+2
                const unsigned short* sb = Esw + (size_t)(s + 2) * 8192;
                unsigned short* db = &Bs[(s + 2) % 3][0];
#pragma unroll
                for (int i = 0; i < 2; ++i)
                    glds16(sb + (w * 2 + i) * 512 + lane * 8, db + (w * 2 + i) * 512);
            }
            const unsigned short* bb = &Bs[s % 3][0];
            if (kcs == 0) {
#pragma unroll
                for (int ni = 0; ni < 8; ++ni) {
                    es[ni] = esq_lds[ss * 128 + ni * 16 + lrow];
                    acc[ni] = (f4v){0.f, 0.f, 0.f, 0.f};
                }
            }
#pragma unroll
            for (int ks = 0; ks < 2; ++ks) {
#pragma unroll
                for (int ni = 0; ni < 8; ++ni) {
                    const int crow = ni * 16 + lrow;
                    s8v bfr = *reinterpret_cast<const s8v*>(
                        &bb[crow * 64 + (((ks * 4 + lk) ^ (crow & 7)) * 8)]);
                    acc[ni] = __builtin_amdgcn_mfma_f32_16x16x32_bf16(
                        a[kcs * 2 + ks], bfr, acc[ni], 0, 0, 0);
                }
            }
            if (kcs == 3) {                          // fold dist into 22-bit keys
#pragma unroll
                for (int ni = 0; ni < 8; ++ni)
#pragma unroll
                    for (int r = 0; r < 4; ++r) {
                        float dv = fmaf(-2.0f, acc[ni][r], es[ni]);
                        unsigned u = __float_as_uint(dv);
                        u = (u & 0x80000000u) ? ~u : (u | 0x80000000u);
                        unsigned key = (u & 0xFFFFFC00u)
                                     | (unsigned)(ss * 128 + ni * 16 + lrow);
                        unsigned cur = best[r];
                        best[r] = key < cur ? key : cur;
                    }
            }
        }
    }

    // ---- cross-lane argmin (wave owns its 16 tokens entirely)
#pragma unroll
    for (int r = 0; r < 4; ++r) {
        unsigned k = best[r];
#pragma unroll
        for (int off = 1; off < 16; off <<= 1) {
            unsigned o = __shfl_xor(k, off, 64);
            k = o < k ? o : k;
        }
        if (lrow == 0) idx_lds[w * 16 + lk * 4 + r] = k & 1023u;
    }
    __syncthreads();

    // ---- histogram (block-dedup: one atomic per distinct code)
    if (t < 128) {
        unsigned my = idx_lds[t];
        int cnt = 0; bool lead = true;
        for (int j = 0; j < 128; ++j) {
            unsigned v = idx_lds[j];
            if (v == my) { ++cnt; if (j < t) lead = false; }
        }
        if (lead) atomicAdd(&counts[my], (unsigned)cnt);
    }

    // ---- fused epilogue: Zq straight-through + diff^2 partials
    {
        const int tok = t & 127, q = t >> 7;         // q = d-quarter
        const unsigned idx = idx_lds[tok];
        const float* ep = E + (size_t)idx * DDIM + q * 64;
        const float* zp = inb + tok + (size_t)q * 64 * HWSZ;
        float* op = out + 1 + (size_t)b * BSTRIDE + (size_t)q * 64 * HWSZ + hw0 + tok;
        double sacc = 0.0;
#pragma unroll 4
        for (int i8 = 0; i8 < 16; ++i8) {
            const float4 ev = *reinterpret_cast<const float4*>(ep + i8 * 4);
            const float* evp = reinterpret_cast<const float*>(&ev);
#pragma unroll
            for (int j = 0; j < 4; ++j) {
                const int d = i8 * 4 + j;
                float ze = zp[(size_t)d * HWSZ];
                float df = __fsub_rn(evp[j], ze);    // fl(zq - ze)
                op[(size_t)d * HWSZ] = __fadd_rn(ze, df);
                sacc += (double)__fmul_rn(df, df);
            }
        }
        sd[t] = sacc;
    }
    __syncthreads();
    for (int off = 256; off; off >>= 1) {
        if (t < off) sd[t] += sd[t + off];
        __syncthreads();
    }
    if (t == 0) partials[blockIdx.x] = sd[0];
}

// ---------------------------------------------------------------- finalize
__global__ __launch_bounds__(256) void k_final(const double* __restrict__ partials,
                                               const unsigned* __restrict__ counts,
                                               float* __restrict__ out) {
    __shared__ double sd[256];
    int t = threadIdx.x;
    sd[t] = partials[t];
    __syncthreads();
    for (int off = 128; off; off >>= 1) {
        if (t < off) sd[t] += sd[t + off];
        __syncthreads();
    }
    double msum = sd[0];
    __syncthreads();

    double es_ = 0.0;
#pragma unroll
    for (int j = 0; j < 4; ++j) {
        unsigned c = counts[t * 4 + j];
        float p = (float)c / 32768.0f;               // exact (div by 2^15)
        float term = __fmul_rn(p, log2f(__fadd_rn(p, 1e-10f)));
        es_ += (double)term;
    }
    sd[t] = es_; __syncthreads();
    for (int off = 128; off; off >>= 1) {
        if (t < off) sd[t] += sd[t + off];
        __syncthreads();
    }
    if (t == 0) {
        float e = (float)(msum / 8388608.0);         // mean over B*D*H*W
        float q = e;                                 // numerically identical in ref
        float loss = __fadd_rn(q, __fmul_rn(0.25f, e));
        float ent = -(float)sd[0];
        float words = exp2f(ent);
        out[0] = loss;
        out[1 + 8388608 + 0] = e;
        out[1 + 8388608 + 1] = q;
        out[1 + 8388608 + 2] = words;
    }
}

// ---------------------------------------------------------------- launch
extern "C" void kernel_launch(void* const* d_in, const int* in_sizes, int n_in,
                              void* d_out, int out_size, void* d_ws, size_t ws_size,
                              hipStream_t stream) {
    const float* in = (const float*)d_in[0];
    const float* E  = (const float*)d_in[1];
    float* out = (float*)d_out;
    char* ws = (char*)d_ws;
    float*          esq      = (float*)(ws + OFF_ESQ);
    unsigned short* Esw      = (unsigned short*)(ws + OFF_SW);
    unsigned*       counts   = (unsigned*)(ws + OFF_CNT);
    double*         partials = (double*)(ws + OFF_PART);

    hipLaunchKernelGGL(k_prep, dim3(128), dim3(256), 0, stream, E, esq, Esw, counts);
    hipLaunchKernelGGL(k_main, dim3(256), dim3(512), 0, stream,
                       in, E, Esw, esq, counts, partials, out);
    hipLaunchKernelGGL(k_final, dim3(1), dim3(256), 0, stream, partials, counts, out);
}